// Round 2
// baseline (1749.496 us; speedup 1.0000x reference)
//
#include <hip/hip_runtime.h>

#define N_PTS 200000
#define C_IN  32
#define C_OUT 64
#define K_NB  27
#define BN_EPS 1e-5f

// ws layout (bytes):
//   [0, 221184)        wtk : float[27][32][64]  (transposed weight)
//   [221184, 221696)   ab  : float[128]         (a[64], b[64])
//   [221696, 221824)   zbuf: float[32]          (zeros for invalid neigh)
//   [262144, +25.6MB)  xt  : float[N_PTS][32]   (transposed input, optional)
#define WS_WTK_OFF  0
#define WS_AB_OFF   221184
#define WS_Z_OFF    221696
#define WS_XT_OFF   262144
#define WS_NEED_XT  (WS_XT_OFF + (size_t)N_PTS * C_IN * sizeof(float))
#define WS_NEED_MIN (WS_Z_OFF + 128)

// ---------- 1. transpose x[c][n] -> xt[n][c] (f32) ----------
__global__ void k_transpose(const float* __restrict__ x, float* __restrict__ xt) {
    int n = blockIdx.x * blockDim.x + threadIdx.x;
    if (n >= N_PTS) return;
    float buf[C_IN];
#pragma unroll
    for (int c = 0; c < C_IN; ++c) buf[c] = x[(long long)c * N_PTS + n];
    float4* dst = (float4*)(xt + (long long)n * C_IN);
#pragma unroll
    for (int q = 0; q < C_IN / 4; ++q)
        dst[q] = ((const float4*)buf)[q];
}

// ---------- 2. transpose weight w[o][c][k] -> wtk[k][c][o] ----------
__global__ void k_wt(const float* __restrict__ w, float* __restrict__ wtk) {
    int i = blockIdx.x * 256 + threadIdx.x;
    if (i >= K_NB * C_IN * C_OUT) return;
    int o = i & 63;
    int r = i >> 6;
    int c = r & 31;
    int k = r >> 5;
    wtk[i] = w[(o * C_IN + c) * K_NB + k];
}

// ---------- 3. conv: out_raw[o][n] = sum_{c,k} w[o][c][k]*x[c][neigh[n][k]] ----------
// USE_XT=true : src = xt[N][32] (contiguous per-point rows)
// USE_XT=false: src = x[32][N]  (fallback when ws too small)
template <bool USE_XT>
__launch_bounds__(256, 1)
__global__ void k_conv(const float* __restrict__ src,
                       const int* __restrict__ neigh,
                       const float* __restrict__ wtk,
                       const float* __restrict__ zbuf,
                       float* __restrict__ out) {
    __shared__ float wt_s[C_IN * C_OUT];       // 8 KB: weight slice for current k
    const int lane = threadIdx.x & 63;         // output channel
    const int wave = threadIdx.x >> 6;
    const int n0   = blockIdx.x * 64 + wave * 16;   // 16 points per wave

    float acc[16];
#pragma unroll
    for (int p = 0; p < 16; ++p) acc[p] = 0.f;

    for (int k = 0; k < K_NB; ++k) {
        __syncthreads();   // previous slice's readers done
#pragma unroll
        for (int j = 0; j < 8; ++j)
            wt_s[threadIdx.x + j * 256] = wtk[k * (C_IN * C_OUT) + threadIdx.x + j * 256];
        __syncthreads();

        int t[16];
#pragma unroll
        for (int p = 0; p < 16; ++p)
            t[p] = neigh[(n0 + p) * K_NB + k];   // int32 on device!

        if (USE_XT) {
            const float* bp[16];
#pragma unroll
            for (int p = 0; p < 16; ++p)
                bp[p] = (t[p] >= 0) ? (src + (long long)t[p] * C_IN) : zbuf;

#pragma unroll
            for (int c4 = 0; c4 < C_IN / 4; ++c4) {
                float4 xq[16];
#pragma unroll
                for (int p = 0; p < 16; ++p)
                    xq[p] = *(const float4*)(bp[p] + c4 * 4);
#pragma unroll
                for (int cc = 0; cc < 4; ++cc) {
                    float wv = wt_s[(c4 * 4 + cc) * C_OUT + lane];
#pragma unroll
                    for (int p = 0; p < 16; ++p) {
                        float xv = (cc == 0) ? xq[p].x : (cc == 1) ? xq[p].y
                                 : (cc == 2) ? xq[p].z : xq[p].w;
                        acc[p] = fmaf(wv, xv, acc[p]);
                    }
                }
            }
        } else {
#pragma unroll
            for (int c = 0; c < C_IN; ++c) {
                float wv = wt_s[c * C_OUT + lane];
#pragma unroll
                for (int p = 0; p < 16; ++p) {
                    float xv = (t[p] >= 0) ? src[(long long)c * N_PTS + t[p]] : 0.f;
                    acc[p] = fmaf(wv, xv, acc[p]);
                }
            }
        }
    }

    // acc[0..15] are 16 consecutive outputs for this lane's channel row
    float4* dst = (float4*)(out + (long long)lane * N_PTS + n0);
#pragma unroll
    for (int q = 0; q < 4; ++q)
        dst[q] = ((const float4*)acc)[q];
}

// ---------- 4. BN stats per channel -> a,b ----------
__launch_bounds__(1024)
__global__ void k_stats(const float* __restrict__ raw,
                        const float* __restrict__ gamma,
                        const float* __restrict__ beta,
                        float* __restrict__ ab) {
    int o = blockIdx.x;
    const float4* row = (const float4*)(raw + (long long)o * N_PTS);
    const int n4 = N_PTS / 4;   // 50000
    float s = 0.f, s2 = 0.f;
    for (int i = threadIdx.x; i < n4; i += 1024) {
        float4 v = row[i];
        s  += v.x + v.y + v.z + v.w;
        s2 += v.x * v.x + v.y * v.y + v.z * v.z + v.w * v.w;
    }
#pragma unroll
    for (int off = 32; off > 0; off >>= 1) {
        s  += __shfl_down(s, off, 64);
        s2 += __shfl_down(s2, off, 64);
    }
    __shared__ float red0[16], red1[16];
    int wv = threadIdx.x >> 6;
    if ((threadIdx.x & 63) == 0) { red0[wv] = s; red1[wv] = s2; }
    __syncthreads();
    if (threadIdx.x == 0) {
        float S = 0.f, S2 = 0.f;
#pragma unroll
        for (int i = 0; i < 16; ++i) { S += red0[i]; S2 += red1[i]; }
        float mean = S / (float)N_PTS;
        float var  = S2 / (float)N_PTS - mean * mean;
        float a = gamma[o] * rsqrtf(var + BN_EPS);
        float b = beta[o] - mean * a;
        ab[o]      = a;
        ab[64 + o] = b;
    }
}

// ---------- 5. normalize + relu, in place on d_out ----------
__global__ void k_norm(float* __restrict__ out, const float* __restrict__ ab) {
    int i = blockIdx.x * 256 + threadIdx.x;    // over float4 elements
    const int total4 = (C_OUT * N_PTS) / 4;
    if (i >= total4) return;
    int o = (i * 4) / N_PTS;
    float a = ab[o], b = ab[64 + o];
    float4 v = ((float4*)out)[i];
    v.x = fmaxf(fmaf(v.x, a, b), 0.f);
    v.y = fmaxf(fmaf(v.y, a, b), 0.f);
    v.z = fmaxf(fmaf(v.z, a, b), 0.f);
    v.w = fmaxf(fmaf(v.w, a, b), 0.f);
    ((float4*)out)[i] = v;
}

extern "C" void kernel_launch(void* const* d_in, const int* in_sizes, int n_in,
                              void* d_out, int out_size, void* d_ws, size_t ws_size,
                              hipStream_t stream) {
    const float* x   = (const float*)d_in[0];
    const int*   nb  = (const int*)d_in[1];     // int64 in ref -> int32 on device
    const float* w   = (const float*)d_in[2];
    const float* gam = (const float*)d_in[3];
    const float* bet = (const float*)d_in[4];
    float* out = (float*)d_out;

    char*  ws   = (char*)d_ws;
    float* wtk  = (float*)(ws + WS_WTK_OFF);
    float* ab   = (float*)(ws + WS_AB_OFF);
    float* zbuf = (float*)(ws + WS_Z_OFF);
    float* xt   = (float*)(ws + WS_XT_OFF);

    const bool use_xt = (ws_size >= WS_NEED_XT);

    hipMemsetAsync(zbuf, 0, C_IN * sizeof(float), stream);
    k_wt<<<(K_NB * C_IN * C_OUT + 255) / 256, 256, 0, stream>>>(w, wtk);

    if (use_xt) {
        k_transpose<<<(N_PTS + 255) / 256, 256, 0, stream>>>(x, xt);
        k_conv<true><<<N_PTS / 64, 256, 0, stream>>>(xt, nb, wtk, zbuf, out);
    } else {
        k_conv<false><<<N_PTS / 64, 256, 0, stream>>>(x, nb, wtk, zbuf, out);
    }

    k_stats<<<C_OUT, 1024, 0, stream>>>(out, gam, bet, ab);
    k_norm<<<((C_OUT * N_PTS) / 4 + 255) / 256, 256, 0, stream>>>(out, ab);
}

// Round 3
// 147.147 us; speedup vs baseline: 11.8895x; 11.8895x over previous
//
#include <hip/hip_runtime.h>

#define N_PTS 200000
#define C_IN  32
#define C_OUT 64
#define K_NB  27
#define BN_EPS 1e-5f

using bf16x8 = __attribute__((ext_vector_type(8))) short;
using f32x4  = __attribute__((ext_vector_type(4))) float;

// ---------------- ws layout (MFMA path) ----------------
//  [0, 114688)            wt  : bf16[28][64][32]   (28th row zeros, prefetch pad)
//  [114688, 115200)       ab  : float[128]         (a[64], b[64])
//  [115200, 119296)       ps  : float[2][512]      (BN partial sums)
//  [131072, +12800064)    xt  : bf16[N+1][32]      (row N = zeros)
//  [12931136, +23200000)  nt  : int32[29][N]       (rows 27,28 = N -> zero row)
#define M_WT_OFF  0
#define M_AB_OFF  114688
#define M_PS_OFF  115200
#define M_XT_OFF  131072
#define M_NT_OFF  (131072 + 12800064)
#define M_WS_NEED ((size_t)M_NT_OFF + 29ull * N_PTS * 4ull)

// ---------------- ws layout (fallback f32 path) ----------------
#define F_WTK_OFF 0
#define F_AB_OFF  221184
#define F_Z_OFF   221696
#define F_PS_OFF  221824

__device__ __forceinline__ unsigned short f2bf(float f) {
    unsigned int u = __float_as_uint(f);
    u = (u + 0x7fffu + ((u >> 16) & 1u)) >> 16;
    return (unsigned short)u;
}

// ---------- prep: x[c][n] -> xt[n][c] bf16, row N zeroed ----------
__global__ void k_prep_x(const float* __restrict__ x, unsigned short* __restrict__ xt) {
    int n = blockIdx.x * 256 + threadIdx.x;
    if (n > N_PTS) return;
    unsigned short row[C_IN];
    if (n == N_PTS) {
#pragma unroll
        for (int c = 0; c < C_IN; ++c) row[c] = 0;
    } else {
#pragma unroll
        for (int c = 0; c < C_IN; ++c) row[c] = f2bf(x[(long long)c * N_PTS + n]);
    }
    uint4* dst = (uint4*)(xt + (long long)n * C_IN);
#pragma unroll
    for (int q = 0; q < 4; ++q) dst[q] = ((const uint4*)row)[q];
}

// ---------- prep: w[o][c][k] -> wt[k][o][c] bf16, k=27 zeros ----------
__global__ void k_prep_w(const float* __restrict__ w, unsigned short* __restrict__ wt) {
    int i = blockIdx.x * 256 + threadIdx.x;
    if (i >= 28 * C_OUT * C_IN) return;
    int c = i & 31, o = (i >> 5) & 63, k = i >> 11;
    wt[i] = (k < K_NB) ? f2bf(w[(o * C_IN + c) * K_NB + k]) : (unsigned short)0;
}

// ---------- prep: neigh[n][k] -> nt[k][n], invalid/pad -> N (zero row) ----------
__global__ void k_prep_n(const int* __restrict__ neigh, int* __restrict__ nt) {
    int n = blockIdx.x * 256 + threadIdx.x;
    if (n >= N_PTS) return;
    int v[K_NB];
#pragma unroll
    for (int k = 0; k < K_NB; ++k) v[k] = neigh[n * K_NB + k];
#pragma unroll
    for (int k = 0; k < K_NB; ++k) {
        int t = v[k];
        nt[(long long)k * N_PTS + n] = (t >= 0 && t < N_PTS) ? t : N_PTS;
    }
    nt[27ll * N_PTS + n] = N_PTS;
    nt[28ll * N_PTS + n] = N_PTS;
}

// ---------- conv via MFMA: out[o][n] = sum_{c,k} W[o][c][k] * xt[nt[k][n]][c] ----------
__launch_bounds__(256, 3)
__global__ void k_conv_mfma(const unsigned short* __restrict__ xt,
                            const int* __restrict__ nt,
                            const unsigned short* __restrict__ wt,
                            float* __restrict__ out) {
    const int lane = threadIdx.x & 63;
    const int wv   = threadIdx.x >> 6;
    const int n0   = blockIdx.x * 256 + wv * 64;
    if (n0 >= N_PTS) return;
    const int l15 = lane & 15, lq = lane >> 4;

    const unsigned short* xt_q = xt + lq * 8;                 // quarter-row base
    const unsigned short* wt_q = wt + l15 * C_IN + lq * 8;    // + k*2048 + ot*512
    const int nbase = n0 + l15;

    f32x4 acc[4][4];   // [g: point-group][ot: o-tile]
#pragma unroll
    for (int g = 0; g < 4; ++g)
#pragma unroll
        for (int ot = 0; ot < 4; ++ot) acc[g][ot] = f32x4{0.f, 0.f, 0.f, 0.f};

    int tb[4];
    bf16x8 bc[4], ac[4];
    {
        int t0[4];
#pragma unroll
        for (int g = 0; g < 4; ++g) t0[g] = nt[nbase + 16 * g];
#pragma unroll
        for (int g = 0; g < 4; ++g) tb[g] = nt[N_PTS + nbase + 16 * g];
#pragma unroll
        for (int g = 0; g < 4; ++g) bc[g] = *(const bf16x8*)(xt_q + (long long)t0[g] * C_IN);
#pragma unroll
        for (int ot = 0; ot < 4; ++ot) ac[ot] = *(const bf16x8*)(wt_q + ot * 512);
    }

    for (int k = 0; k < K_NB; ++k) {
        // prefetch t for k+2 (rows padded to 29)
        int tn[4];
#pragma unroll
        for (int g = 0; g < 4; ++g) tn[g] = nt[(long long)(k + 2) * N_PTS + nbase + 16 * g];
        // prefetch A for k+1 (rows padded to 28)
        bf16x8 an[4];
#pragma unroll
        for (int ot = 0; ot < 4; ++ot) an[ot] = *(const bf16x8*)(wt_q + (k + 1) * 2048 + ot * 512);
        // prefetch B for k+1
        bf16x8 bn[4];
#pragma unroll
        for (int g = 0; g < 4; ++g) bn[g] = *(const bf16x8*)(xt_q + (long long)tb[g] * C_IN);

#pragma unroll
        for (int g = 0; g < 4; ++g)
#pragma unroll
            for (int ot = 0; ot < 4; ++ot)
                acc[g][ot] = __builtin_amdgcn_mfma_f32_16x16x32_bf16(ac[ot], bc[g], acc[g][ot], 0, 0, 0);

#pragma unroll
        for (int g = 0; g < 4; ++g) { bc[g] = bn[g]; tb[g] = tn[g]; }
#pragma unroll
        for (int ot = 0; ot < 4; ++ot) ac[ot] = an[ot];
    }

    // D layout (m89): col = lane&15 (point), row = lq*4 + r (channel within tile)
#pragma unroll
    for (int ot = 0; ot < 4; ++ot)
#pragma unroll
        for (int r = 0; r < 4; ++r) {
            float* o = out + (long long)(ot * 16 + lq * 4 + r) * N_PTS + n0 + l15;
#pragma unroll
            for (int g = 0; g < 4; ++g) o[16 * g] = acc[g][ot][r];
        }
}

// ---------- fallback f32 conv (small ws) ----------
__global__ void k_wt_f32(const float* __restrict__ w, float* __restrict__ wtk) {
    int i = blockIdx.x * 256 + threadIdx.x;
    if (i >= K_NB * C_IN * C_OUT) return;
    int o = i & 63, r = i >> 6, c = r & 31, k = r >> 5;
    wtk[i] = w[(o * C_IN + c) * K_NB + k];
}

__launch_bounds__(256, 1)
__global__ void k_conv_f32(const float* __restrict__ src, const int* __restrict__ neigh,
                           const float* __restrict__ wtk, float* __restrict__ out) {
    __shared__ float wt_s[C_IN * C_OUT];
    const int lane = threadIdx.x & 63;
    const int wave = threadIdx.x >> 6;
    const int n0   = blockIdx.x * 64 + wave * 16;
    float acc[16];
#pragma unroll
    for (int p = 0; p < 16; ++p) acc[p] = 0.f;
    for (int k = 0; k < K_NB; ++k) {
        __syncthreads();
#pragma unroll
        for (int j = 0; j < 8; ++j)
            wt_s[threadIdx.x + j * 256] = wtk[k * (C_IN * C_OUT) + threadIdx.x + j * 256];
        __syncthreads();
        int t[16];
#pragma unroll
        for (int p = 0; p < 16; ++p) t[p] = neigh[(n0 + p) * K_NB + k];
#pragma unroll
        for (int c = 0; c < C_IN; ++c) {
            float wv = wt_s[c * C_OUT + lane];
#pragma unroll
            for (int p = 0; p < 16; ++p) {
                float xv = (t[p] >= 0) ? src[(long long)c * N_PTS + t[p]] : 0.f;
                acc[p] = fmaf(wv, xv, acc[p]);
            }
        }
    }
    float4* dst = (float4*)(out + (long long)lane * N_PTS + n0);
#pragma unroll
    for (int q = 0; q < 4; ++q) dst[q] = ((const float4*)acc)[q];
}

// ---------- BN stats, 2-stage ----------
__global__ void k_stats1(const float* __restrict__ raw, float* __restrict__ ps) {
    int o = blockIdx.x & 63, sl = blockIdx.x >> 6;     // 8 slices per channel
    const int per = N_PTS / 8;                          // 25000
    const float4* row = (const float4*)(raw + (long long)o * N_PTS + (long long)sl * per);
    float s = 0.f, s2 = 0.f;
    for (int i = threadIdx.x; i < per / 4; i += 256) {
        float4 v = row[i];
        s  += v.x + v.y + v.z + v.w;
        s2 += v.x * v.x + v.y * v.y + v.z * v.z + v.w * v.w;
    }
#pragma unroll
    for (int off = 32; off > 0; off >>= 1) {
        s  += __shfl_down(s, off, 64);
        s2 += __shfl_down(s2, off, 64);
    }
    __shared__ float r0[4], r1[4];
    int wv = threadIdx.x >> 6;
    if ((threadIdx.x & 63) == 0) { r0[wv] = s; r1[wv] = s2; }
    __syncthreads();
    if (threadIdx.x == 0) {
        ps[blockIdx.x]       = r0[0] + r0[1] + r0[2] + r0[3];
        ps[512 + blockIdx.x] = r1[0] + r1[1] + r1[2] + r1[3];
    }
}

__global__ void k_stats2(const float* __restrict__ ps, const float* __restrict__ gamma,
                         const float* __restrict__ beta, float* __restrict__ ab) {
    int o = threadIdx.x;   // 64 threads
    float S = 0.f, S2 = 0.f;
#pragma unroll
    for (int sl = 0; sl < 8; ++sl) {
        S  += ps[sl * 64 + o];
        S2 += ps[512 + sl * 64 + o];
    }
    float mean = S / (float)N_PTS;
    float var  = S2 / (float)N_PTS - mean * mean;
    float a = gamma[o] * rsqrtf(var + BN_EPS);
    float b = beta[o] - mean * a;
    ab[o]      = a;
    ab[64 + o] = b;
}

// ---------- normalize + relu, in place ----------
__global__ void k_norm(float* __restrict__ out, const float* __restrict__ ab) {
    int i = blockIdx.x * 256 + threadIdx.x;
    const int total4 = (C_OUT * N_PTS) / 4;
    if (i >= total4) return;
    int o = (i * 4) / N_PTS;
    float a = ab[o], b = ab[64 + o];
    float4 v = ((float4*)out)[i];
    v.x = fmaxf(fmaf(v.x, a, b), 0.f);
    v.y = fmaxf(fmaf(v.y, a, b), 0.f);
    v.z = fmaxf(fmaf(v.z, a, b), 0.f);
    v.w = fmaxf(fmaf(v.w, a, b), 0.f);
    ((float4*)out)[i] = v;
}

extern "C" void kernel_launch(void* const* d_in, const int* in_sizes, int n_in,
                              void* d_out, int out_size, void* d_ws, size_t ws_size,
                              hipStream_t stream) {
    const float* x   = (const float*)d_in[0];
    const int*   nb  = (const int*)d_in[1];     // int64 in ref -> int32 on device
    const float* w   = (const float*)d_in[2];
    const float* gam = (const float*)d_in[3];
    const float* bet = (const float*)d_in[4];
    float* out = (float*)d_out;
    char* ws = (char*)d_ws;

    if (ws_size >= M_WS_NEED) {
        unsigned short* wt = (unsigned short*)(ws + M_WT_OFF);
        float*          ab = (float*)(ws + M_AB_OFF);
        float*          ps = (float*)(ws + M_PS_OFF);
        unsigned short* xt = (unsigned short*)(ws + M_XT_OFF);
        int*            nt = (int*)(ws + M_NT_OFF);

        k_prep_x<<<(N_PTS + 256) / 256, 256, 0, stream>>>(x, xt);
        k_prep_w<<<(28 * C_OUT * C_IN + 255) / 256, 256, 0, stream>>>(w, wt);
        k_prep_n<<<(N_PTS + 255) / 256, 256, 0, stream>>>(nb, nt);
        k_conv_mfma<<<(N_PTS + 255) / 256, 256, 0, stream>>>(xt, nt, wt, out);
        k_stats1<<<512, 256, 0, stream>>>(out, ps);
        k_stats2<<<1, 64, 0, stream>>>(ps, gam, bet, ab);
        k_norm<<<((C_OUT * N_PTS) / 4 + 255) / 256, 256, 0, stream>>>(out, ab);
    } else {
        float* wtk  = (float*)(ws + F_WTK_OFF);
        float* ab   = (float*)(ws + F_AB_OFF);
        float* zbuf = (float*)(ws + F_Z_OFF);
        float* ps   = (float*)(ws + F_PS_OFF);
        hipMemsetAsync(zbuf, 0, C_IN * sizeof(float), stream);
        k_wt_f32<<<(K_NB * C_IN * C_OUT + 255) / 256, 256, 0, stream>>>(w, wtk);
        k_conv_f32<<<N_PTS / 64, 256, 0, stream>>>(x, nb, wtk, out);
        k_stats1<<<512, 256, 0, stream>>>(out, ps);
        k_stats2<<<1, 64, 0, stream>>>(ps, gam, bet, ab);
        k_norm<<<((C_OUT * N_PTS) / 4 + 255) / 256, 256, 0, stream>>>(out, ab);
    }
}